// Round 3
// baseline (95.302 us; speedup 1.0000x reference)
//
#include <hip/hip_runtime.h>

// FK_Velocity_Loss: pos_loss = vel_loss = mean((out_fk - gt_fk)^2)
// (gt_prev_pose cancels exactly: (o - p) - (g - p) = o - g)
//
// R3: fully-coalesced loads. A wave reads 64 consecutive float4 = 1KB = 4
// chains per instruction (the m13 6.3TB/s pattern). 16 lanes per chain:
// lane l holds row (l&3) of matrix (l>>2). FK chain v <- Mj*v done with
// ds_swizzle immediate broadcasts within each 16-lane group; after the last
// step, lanes with (lane&15)<3 hold the final translation components.

#define N_CHAINS 800000              // 400000 rows x 2 chains
#define UNITS (N_CHAINS / 4)         // 200000 wave-units (4 chains each)
#define WAVES 12500
#define ITERS (UNITS / WAVES)        // 16, exact
#define BLOCK 256
#define BLOCKS (WAVES / 4)           // 3125
#define MEAN_DIV (400000.0 * 2.0 * 3.0)

__global__ void fk_zero_acc(double* acc) { acc[0] = 0.0; }

// Broadcast lane ((l&0x10) | (4Q+C)) of the 32-lane half to all lanes of its
// 16-lane group. BitMode ds_swizzle: offset = (or<<5) | and, and=0x10.
template <int Q, int C>
__device__ __forceinline__ float swz(float v) {
    return __builtin_bit_cast(float,
        __builtin_amdgcn_ds_swizzle(__builtin_bit_cast(int, v),
                                    ((4 * Q + C) << 5) | 0x10));
}

// One chain step: v_new = M_row . v, where v's 4 components live in the
// lanes of quad Q (rows 0..3) of this 16-lane group.
template <int Q>
__device__ __forceinline__ float step(float4 m, float v) {
    float a0 = swz<Q, 0>(v), a1 = swz<Q, 1>(v), a2 = swz<Q, 2>(v), a3 = swz<Q, 3>(v);
    return m.x * a0 + m.y * a1 + m.z * a2 + m.w * a3;
}

__global__ __launch_bounds__(BLOCK) void fk_loss_kernel(const float4* __restrict__ o4,
                                                        const float4* __restrict__ g4,
                                                        double* __restrict__ acc) {
    const int tid = blockIdx.x * BLOCK + threadIdx.x;
    const int wave = tid >> 6;
    const int lane = threadIdx.x & 63;
    const long base = (long)wave * ITERS * 64 + lane;

    float ss = 0.0f;
    float4 mo = o4[base], mg = g4[base];   // prefetch iter 0
#pragma unroll 1
    for (int it = 0; it < ITERS; ++it) {
        float4 no, ng;
        if (it + 1 < ITERS) {
            no = o4[base + (it + 1) * 64];
            ng = g4[base + (it + 1) * 64];
        }
        // chain: v = M3[:,3]; v = M2*v; v = M1*v; v = M0*v
        float vo = mo.w, vg = mg.w;        // meaningful in quad 3 lanes
        vo = step<3>(mo, vo); vg = step<3>(mg, vg);
        vo = step<2>(mo, vo); vg = step<2>(mg, vg);
        vo = step<1>(mo, vo); vg = step<1>(mg, vg);
        float d = vo - vg;                 // final components in lanes (l&15)<4
        ss += ((lane & 15) < 3) ? d * d : 0.0f;
        mo = no; mg = ng;
    }

    // wave64 shuffle reduce
#pragma unroll
    for (int off = 32; off > 0; off >>= 1) ss += __shfl_down(ss, off, 64);
    __shared__ float part[BLOCK / 64];
    const int w = threadIdx.x >> 6;
    if ((threadIdx.x & 63) == 0) part[w] = ss;
    __syncthreads();
    if (threadIdx.x == 0) {
        float b = part[0] + part[1] + part[2] + part[3];
        atomicAdd(acc, (double)b);  // one device-scope f64 atomic per block
    }
}

__global__ void fk_finalize(const double* __restrict__ acc, float* __restrict__ out) {
    float v = (float)(acc[0] / MEAN_DIV);
    out[0] = v;  // pos_loss
    out[1] = v;  // vel_loss (identical: gt_prev cancels)
}

extern "C" void kernel_launch(void* const* d_in, const int* in_sizes, int n_in,
                              void* d_out, int out_size, void* d_ws, size_t ws_size,
                              hipStream_t stream) {
    const float4* output_pose = (const float4*)d_in[0];
    const float4* gt_pose     = (const float4*)d_in[1];
    // d_in[2] (gt_prev_pose) and d_in[3] (gt_pos) are not needed.
    float* out = (float*)d_out;
    double* acc = (double*)d_ws;

    fk_zero_acc<<<1, 1, 0, stream>>>(acc);
    fk_loss_kernel<<<BLOCKS, BLOCK, 0, stream>>>(output_pose, gt_pose, acc);
    fk_finalize<<<1, 1, 0, stream>>>(acc, out);
}

// Round 4
// 75.738 us; speedup vs baseline: 1.2583x; 1.2583x over previous
//
#include <hip/hip_runtime.h>

// FK_Velocity_Loss: pos_loss = vel_loss = mean((out_fk - gt_fk)^2)
// (gt_prev_pose cancels exactly: (o - p) - (g - p) = o - g)
//
// R4 = R2 layout (4 lanes/chain, DPP quad-broadcast mat-vec — VALU-only,
// no LDS pipe) + explicit 1-deep software pipeline (next iter's 8 float4
// loads issued before current compute) + atomic-free reduction:
// per-block partials to d_ws, one-block finalize. 2 kernels, no zero pass.

#define N_CHAINS 800000                  // 400000 rows x 2 chains
#define ITERS 4
#define BLOCK 256
#define BLOCKS (N_CHAINS * 4 / ITERS / BLOCK)   // 3125, exact
#define CHAIN_STRIDE (N_CHAINS / ITERS)         // 200000
#define MEAN_DIV (400000.0 * 2.0 * 3.0)

// Broadcast lane (quad_base + I) across the quad. DPP quad_perm, 1-cycle VALU.
template <int I>
__device__ __forceinline__ float qb(float x) {
    return __builtin_bit_cast(float,
        __builtin_amdgcn_mov_dpp(__builtin_bit_cast(int, x),
                                 I | (I << 2) | (I << 4) | (I << 6),
                                 0xF, 0xF, true));
}

// Lane holds row k of M0..M3. Returns component k of (M0*M1*M2*M3)[:,3],
// computed right-to-left: v = M3[:,3]; v = M2*v; v = M1*v; v = M0*v.
__device__ __forceinline__ float fk_elem(float4 m0, float4 m1, float4 m2, float4 m3) {
    float v = m3.w;
    float v0, v1, v2, v3;
    v0 = qb<0>(v); v1 = qb<1>(v); v2 = qb<2>(v); v3 = qb<3>(v);
    v = m2.x * v0 + m2.y * v1 + m2.z * v2 + m2.w * v3;
    v0 = qb<0>(v); v1 = qb<1>(v); v2 = qb<2>(v); v3 = qb<3>(v);
    v = m1.x * v0 + m1.y * v1 + m1.z * v2 + m1.w * v3;
    v0 = qb<0>(v); v1 = qb<1>(v); v2 = qb<2>(v); v3 = qb<3>(v);
    v = m0.x * v0 + m0.y * v1 + m0.z * v2 + m0.w * v3;
    return v;
}

__global__ __launch_bounds__(BLOCK) void fk_loss_kernel(const float4* __restrict__ o4,
                                                        const float4* __restrict__ g4,
                                                        float* __restrict__ partial) {
    const int tid = blockIdx.x * BLOCK + threadIdx.x;
    const int k = tid & 3;          // row within quad
    const int q = tid >> 2;         // base chain index

    const float4* po = o4 + (size_t)q * 16 + k;
    const float4* pg = g4 + (size_t)q * 16 + k;
    float4 o0 = po[0], o1 = po[4], o2 = po[8], o3 = po[12];
    float4 g0 = pg[0], g1 = pg[4], g2 = pg[8], g3 = pg[12];

    float ss = 0.0f;
#pragma unroll
    for (int it = 0; it < ITERS; ++it) {
        float4 no0, no1, no2, no3, ng0, ng1, ng2, ng3;
        if (it + 1 < ITERS) {       // issue next iter's loads BEFORE compute
            const size_t off = ((size_t)q + (size_t)(it + 1) * CHAIN_STRIDE) * 16 + k;
            const float4* qo = o4 + off;
            const float4* qg = g4 + off;
            no0 = qo[0]; no1 = qo[4]; no2 = qo[8]; no3 = qo[12];
            ng0 = qg[0]; ng1 = qg[4]; ng2 = qg[8]; ng3 = qg[12];
        }
        float fo = fk_elem(o0, o1, o2, o3);
        float fg = fk_elem(g0, g1, g2, g3);
        float d = fo - fg;
        ss += (k < 3) ? d * d : 0.0f;
        o0 = no0; o1 = no1; o2 = no2; o3 = no3;
        g0 = ng0; g1 = ng1; g2 = ng2; g3 = ng3;
    }

    // wave64 shuffle reduce, then block reduce, one store per block
#pragma unroll
    for (int off = 32; off > 0; off >>= 1) ss += __shfl_down(ss, off, 64);
    __shared__ float part[BLOCK / 64];
    if ((threadIdx.x & 63) == 0) part[threadIdx.x >> 6] = ss;
    __syncthreads();
    if (threadIdx.x == 0)
        partial[blockIdx.x] = part[0] + part[1] + part[2] + part[3];
}

__global__ __launch_bounds__(BLOCK) void fk_finalize(const float* __restrict__ partial,
                                                     float* __restrict__ out) {
    double s = 0.0;
    for (int i = threadIdx.x; i < BLOCKS; i += BLOCK) s += (double)partial[i];
    // reduce 256 lanes of doubles via float path is lossy; use shared doubles
    __shared__ double dpart[BLOCK / 64];
#pragma unroll
    for (int off = 32; off > 0; off >>= 1) s += __shfl_down(s, off, 64);
    if ((threadIdx.x & 63) == 0) dpart[threadIdx.x >> 6] = s;
    __syncthreads();
    if (threadIdx.x == 0) {
        double b = dpart[0] + dpart[1] + dpart[2] + dpart[3];
        float v = (float)(b / MEAN_DIV);
        out[0] = v;  // pos_loss
        out[1] = v;  // vel_loss (identical: gt_prev cancels)
    }
}

extern "C" void kernel_launch(void* const* d_in, const int* in_sizes, int n_in,
                              void* d_out, int out_size, void* d_ws, size_t ws_size,
                              hipStream_t stream) {
    const float4* output_pose = (const float4*)d_in[0];
    const float4* gt_pose     = (const float4*)d_in[1];
    // d_in[2] (gt_prev_pose) and d_in[3] (gt_pos) are not needed.
    float* out = (float*)d_out;
    float* partial = (float*)d_ws;   // BLOCKS floats, fully overwritten each call

    fk_loss_kernel<<<BLOCKS, BLOCK, 0, stream>>>(output_pose, gt_pose, partial);
    fk_finalize<<<1, BLOCK, 0, stream>>>(partial, out);
}